// Round 10
// baseline (99.431 us; speedup 1.0000x reference)
//
#include <hip/hip_runtime.h>

static constexpr int N_NODES = 250000;
static constexpr int N_EDGES = 5000000;

// ---- single-pass counting-sort by dst>>9 into 512-node buckets ----
static constexpr int NB    = 512;                       // partition blocks
static constexpr int CHUNK = 9768;                      // per-block edges; NB*CHUNK >= N_EDGES
static constexpr int NBK   = 512;                       // buckets (dst>>9); 489 used
static constexpr int NBUCK = (N_NODES + 511) / 512;     // 489 consumer blocks
static constexpr int BCAP  = 12288;                     // per-bucket region (mean 10225, +20 sigma)

// pack: bits 0..17 = src (N < 2^18), bits 20..28 = dst & 511
__device__ __forceinline__ unsigned pack_edge(unsigned s, unsigned d) {
    return s | ((d & 511u) << 20);
}

// Single-pass partition: LDS histogram -> scan -> device reservation ->
// LDS bucket-scatter -> coalesced per-bucket run copy-out.  1024 threads.
__global__ void __launch_bounds__(1024, 8)
k_part_sp(const int* __restrict__ src, const int* __restrict__ dst,
          unsigned* __restrict__ glen, unsigned* __restrict__ part,
          uint2* __restrict__ spill) {
    __shared__ unsigned h[NBK];       // bucket counts (preserved)
    __shared__ unsigned loffE[NBK];   // exclusive scan
    __shared__ unsigned cur[NBK];     // scatter cursors
    __shared__ unsigned gb[NBK];      // reserved global offset within bucket region
    __shared__ unsigned ebuf[CHUNK];  // 38.2 KB bucket-ordered edges
    const int t = threadIdx.x;
    const int beg = blockIdx.x * CHUNK;
    const int end = min(beg + CHUNK, N_EDGES);

    if (t < NBK) h[t] = 0;
    __syncthreads();

    // ---- phase A: histogram dst buckets ----
    for (int e = beg + t * 4; e < end; e += 4096) {
        if (e + 4 <= end) {
            int4 d4 = *(const int4*)(dst + e);
            atomicAdd(&h[((unsigned)d4.x) >> 9], 1u);
            atomicAdd(&h[((unsigned)d4.y) >> 9], 1u);
            atomicAdd(&h[((unsigned)d4.z) >> 9], 1u);
            atomicAdd(&h[((unsigned)d4.w) >> 9], 1u);
        } else {
            for (int j = 0; j < 4 && e + j < end; ++j)
                atomicAdd(&h[((unsigned)dst[e + j]) >> 9], 1u);
        }
    }
    __syncthreads();

    // ---- phase B: block scan (threads < NBK) + one device reservation per bucket ----
    unsigned v = 0;
    if (t < NBK) { v = h[t]; loffE[t] = v; }
    __syncthreads();
    for (int off = 1; off < NBK; off <<= 1) {
        unsigned a = 0;
        if (t < NBK && t >= off) a = loffE[t - off];
        __syncthreads();
        if (t < NBK) loffE[t] += a;
        __syncthreads();
    }
    if (t < NBK) {
        loffE[t] -= v;              // exclusive
        cur[t] = loffE[t];
        gb[t] = v ? atomicAdd(&glen[t], v) : 0u;   // reserve once per (block,bucket)
    }
    __syncthreads();

    // ---- phase C: re-read edges (L2-warm), scatter into LDS by bucket ----
    for (int e = beg + t * 4; e < end; e += 4096) {
        if (e + 4 <= end) {
            int4 d4 = *(const int4*)(dst + e);
            int4 s4 = *(const int4*)(src + e);
            #pragma unroll
            for (int j = 0; j < 4; ++j) {
                int dd = j == 0 ? d4.x : j == 1 ? d4.y : j == 2 ? d4.z : d4.w;
                int ss = j == 0 ? s4.x : j == 1 ? s4.y : j == 2 ? s4.z : s4.w;
                unsigned b = ((unsigned)dd) >> 9;
                ebuf[atomicAdd(&cur[b], 1u)] = pack_edge((unsigned)ss, (unsigned)dd);
            }
        } else {
            for (int j = 0; j < 4 && e + j < end; ++j) {
                unsigned dd = (unsigned)dst[e + j], ss = (unsigned)src[e + j];
                ebuf[atomicAdd(&cur[dd >> 9], 1u)] = pack_edge(ss, dd);
            }
        }
    }
    __syncthreads();

    // ---- phase D: coalesced per-bucket run copy-out (+ spill, never in practice) ----
    const int g  = t >> 4;     // 64 groups of 16 lanes (groups never straddle a wave)
    const int gl = t & 15;
    for (int b = g; b < NBK; b += 64) {
        unsigned n = h[b];
        if (!n) continue;
        unsigned lo = loffE[b], base = gb[b];
        unsigned room = (base < (unsigned)BCAP) ? min(n, (unsigned)BCAP - base) : 0u;
        unsigned* dstp = part + (size_t)b * BCAP + base;
        for (unsigned i = gl; i < room; i += 16) dstp[i] = ebuf[lo + i];
        unsigned nsp = n - room;
        if (nsp) {   // overflow -> spill (uint2: src, full dst)
            unsigned spos = 0;
            if (gl == 0) spos = atomicAdd(&glen[NBK], nsp);
            spos = __shfl(spos, (int)((t & 63) & ~15), 64);
            for (unsigned i = gl; i < nsp; i += 16) {
                unsigned pe = ebuf[lo + room + i];
                spill[spos + i] = make_uint2(pe & 0x3FFFFu, ((unsigned)b << 9) | (pe >> 20));
            }
        }
    }
}

// 8-deep batched consumer loop (1024 threads): load 2x uint4, unpack 8,
// then EDGE_OP8 applies the op to all 8 with gathers groupable before atomics.
#define BUCKET_EDGE_LOOP8(EDGE_OP8, EDGE_OP1)                                  \
    const unsigned st = (unsigned)blockIdx.x * (unsigned)BCAP;                 \
    const unsigned tot = min(glen[blockIdx.x], (unsigned)BCAP);                \
    const unsigned a1 = st + (tot & ~7u);                                      \
    for (unsigned k = st + threadIdx.x * 8u; k < a1; k += 8192u) {             \
        uint4 q0 = *(const uint4*)(part + k);                                  \
        uint4 q1 = *(const uint4*)(part + k + 4);                              \
        unsigned p_[8] = { q0.x, q0.y, q0.z, q0.w, q1.x, q1.y, q1.z, q1.w };   \
        EDGE_OP8(p_)                                                           \
    }                                                                          \
    for (unsigned k = a1 + threadIdx.x; k < st + tot; k += 1024u) {            \
        unsigned p = part[k]; EDGE_OP1(p);                                     \
    }

// deg per node (LDS counts) fused with dinv = rsqrt(deg), xs = x*dinv
__global__ void __launch_bounds__(1024, 8)
k_deg_dinv(const unsigned* __restrict__ part, const unsigned* __restrict__ glen,
           const uint2* __restrict__ spill,
           const float* __restrict__ x,
           float* __restrict__ dinv, float* __restrict__ xs) {
    __shared__ unsigned cnt[512];
    if (threadIdx.x < 512) cnt[threadIdx.x] = 0;
    __syncthreads();
    #define DEG8(p_) _Pragma("unroll") for (int j = 0; j < 8; ++j) \
        atomicAdd(&cnt[(p_[j] >> 20) & 511u], 1u);
    #define DEG1(p) atomicAdd(&cnt[((p) >> 20) & 511u], 1u)
    BUCKET_EDGE_LOOP8(DEG8, DEG1)
    #undef DEG8
    #undef DEG1
    unsigned sl = glen[NBK];
    for (unsigned k = threadIdx.x; k < sl; k += 1024u) {
        uint2 e = spill[k];
        if ((e.y >> 9) == (unsigned)blockIdx.x) atomicAdd(&cnt[e.y & 511u], 1u);
    }
    __syncthreads();
    if (threadIdx.x < 512) {
        int n = blockIdx.x * 512 + (int)threadIdx.x;
        if (n < N_NODES) {
            float di = rsqrtf((float)cnt[threadIdx.x] + 1.0f);  // +1 self-loop
            dinv[n] = di;
            xs[n] = x[n] * di;
        }
    }
}

// layer-1 aggregation + fused 16-wide MLP epilogue
__global__ void __launch_bounds__(1024, 8)
k_agg1(const unsigned* __restrict__ part, const unsigned* __restrict__ glen,
       const uint2* __restrict__ spill,
       const float* __restrict__ xs, const float* __restrict__ dinv,
       const float* __restrict__ W1, const float* __restrict__ b1,
       const float* __restrict__ W2, const float* __restrict__ b2,
       float* __restrict__ u, float* __restrict__ out) {
    __shared__ float acc[512];
    if (threadIdx.x < 512) acc[threadIdx.x] = 0.f;
    __syncthreads();
    // 8 gathers issued before the 8 LDS atomics -> 8 outstanding loads/thread
    #define AGG8(p_) {                                                         \
        float v_[8];                                                           \
        _Pragma("unroll") for (int j = 0; j < 8; ++j) v_[j] = xs[p_[j] & 0x3FFFFu]; \
        _Pragma("unroll") for (int j = 0; j < 8; ++j)                          \
            atomicAdd(&acc[(p_[j] >> 20) & 511u], v_[j]); }
    #define AGG1(p) atomicAdd(&acc[((p) >> 20) & 511u], xs[(p) & 0x3FFFFu])
    BUCKET_EDGE_LOOP8(AGG8, AGG1)
    #undef AGG8
    #undef AGG1
    unsigned sl = glen[NBK];
    for (unsigned k = threadIdx.x; k < sl; k += 1024u) {
        uint2 e = spill[k];
        if ((e.y >> 9) == (unsigned)blockIdx.x) atomicAdd(&acc[e.y & 511u], xs[e.x]);
    }
    __syncthreads();
    if (threadIdx.x < 512) {
        int n = blockIdx.x * 512 + (int)threadIdx.x;
        if (n < N_NODES) {
            float di = dinv[n];
            float sv = di * (acc[threadIdx.x] + xs[n]);
            float t = 0.f;
            #pragma unroll
            for (int k = 0; k < 16; ++k)
                t = fmaf(fmaxf(fmaf(sv, W1[k], b1[k]), 0.f), W2[k], t);
            u[n] = t * di;
            out[n] = b2[0] + t * di * di;   // layer-2 self-loop + bias
        }
    }
}

// layer-2 aggregation: out += dinv * sum(u[src])
__global__ void __launch_bounds__(1024, 8)
k_agg2(const unsigned* __restrict__ part, const unsigned* __restrict__ glen,
       const uint2* __restrict__ spill,
       const float* __restrict__ u, const float* __restrict__ dinv,
       float* __restrict__ out) {
    __shared__ float acc[512];
    if (threadIdx.x < 512) acc[threadIdx.x] = 0.f;
    __syncthreads();
    #define AGG8(p_) {                                                         \
        float v_[8];                                                           \
        _Pragma("unroll") for (int j = 0; j < 8; ++j) v_[j] = u[p_[j] & 0x3FFFFu]; \
        _Pragma("unroll") for (int j = 0; j < 8; ++j)                          \
            atomicAdd(&acc[(p_[j] >> 20) & 511u], v_[j]); }
    #define AGG1(p) atomicAdd(&acc[((p) >> 20) & 511u], u[(p) & 0x3FFFFu])
    BUCKET_EDGE_LOOP8(AGG8, AGG1)
    #undef AGG8
    #undef AGG1
    unsigned sl = glen[NBK];
    for (unsigned k = threadIdx.x; k < sl; k += 1024u) {
        uint2 e = spill[k];
        if ((e.y >> 9) == (unsigned)blockIdx.x) atomicAdd(&acc[e.y & 511u], u[e.x]);
    }
    __syncthreads();
    if (threadIdx.x < 512) {
        int n = blockIdx.x * 512 + (int)threadIdx.x;
        if (n < N_NODES) out[n] += dinv[n] * acc[threadIdx.x];
    }
}

// ---- fallback path (device atomics) if ws is too small ----
__global__ void f_init(float* __restrict__ deg) {
    int n = blockIdx.x * blockDim.x + threadIdx.x;
    if (n < N_NODES) deg[n] = 1.0f;
}
__global__ void f_deg(const int* __restrict__ dst, float* __restrict__ deg) {
    int e = blockIdx.x * blockDim.x + threadIdx.x;
    if (e < N_EDGES) atomicAdd(&deg[dst[e]], 1.0f);
}
__global__ void f_node1(const float* __restrict__ x, const float* __restrict__ deg,
                        float* __restrict__ dinv, float* __restrict__ xs,
                        float* __restrict__ s) {
    int n = blockIdx.x * blockDim.x + threadIdx.x;
    if (n < N_NODES) {
        float di = rsqrtf(deg[n]);
        float xv = x[n];
        dinv[n] = di; xs[n] = xv * di; s[n] = xv * di * di;
    }
}
__global__ void f_sc1(const int* __restrict__ src, const int* __restrict__ dst,
                      const float* __restrict__ xs, const float* __restrict__ dinv,
                      float* __restrict__ s) {
    int e = blockIdx.x * blockDim.x + threadIdx.x;
    if (e < N_EDGES) atomicAdd(&s[dst[e]], xs[src[e]] * dinv[dst[e]]);
}
__global__ void f_node2(const float* __restrict__ s, const float* __restrict__ dinv,
                        const float* __restrict__ W1, const float* __restrict__ b1,
                        const float* __restrict__ W2, const float* __restrict__ b2,
                        float* __restrict__ u, float* __restrict__ out) {
    int n = blockIdx.x * blockDim.x + threadIdx.x;
    if (n < N_NODES) {
        float sv = s[n], acc = 0.0f;
        #pragma unroll
        for (int k = 0; k < 16; ++k)
            acc = fmaf(fmaxf(fmaf(sv, W1[k], b1[k]), 0.f), W2[k], acc);
        float di = dinv[n];
        u[n] = acc * di; out[n] = b2[0] + acc * di * di;
    }
}
__global__ void f_sc2(const int* __restrict__ src, const int* __restrict__ dst,
                      const float* __restrict__ u, const float* __restrict__ dinv,
                      float* __restrict__ out) {
    int e = blockIdx.x * blockDim.x + threadIdx.x;
    if (e < N_EDGES) atomicAdd(&out[dst[e]], u[src[e]] * dinv[dst[e]]);
}

extern "C" void kernel_launch(void* const* d_in, const int* in_sizes, int n_in,
                              void* d_out, int out_size, void* d_ws, size_t ws_size,
                              hipStream_t stream) {
    const float* x  = (const float*)d_in[0];
    const int*   ei = (const int*)d_in[1];
    const float* W1 = (const float*)d_in[2];
    const float* b1 = (const float*)d_in[3];
    const float* W2 = (const float*)d_in[4];
    const float* b2 = (const float*)d_in[5];
    float* out = (float*)d_out;
    const int* src = ei;
    const int* dst = ei + N_EDGES;

    // ws layout (u32 units): part[NBK*BCAP] | spill[N_EDGES uint2] | glen[520] | xs | dinv | u
    const size_t partN  = (size_t)NBK * BCAP;              // 6,291,456
    const size_t spillN = (size_t)N_EDGES * 2;             // uint2
    const size_t need   = (partN + spillN + 520 + 3 * (size_t)N_NODES) * 4;

    if (ws_size >= need) {
        unsigned* part  = (unsigned*)d_ws;
        uint2*    spill = (uint2*)(part + partN);
        unsigned* glen  = (unsigned*)(part + partN + spillN);
        float*    xs    = (float*)(glen + 520);
        float*    dinv  = xs + N_NODES;
        float*    u     = dinv + N_NODES;

        hipMemsetAsync(glen, 0, 520 * sizeof(unsigned), stream);  // replaces z_init kernel
        k_part_sp <<<NB, 1024, 0, stream>>>(src, dst, glen, part, spill);
        k_deg_dinv<<<NBUCK, 1024, 0, stream>>>(part, glen, spill, x, dinv, xs);
        k_agg1    <<<NBUCK, 1024, 0, stream>>>(part, glen, spill, xs, dinv, W1, b1, W2, b2, u, out);
        k_agg2    <<<NBUCK, 1024, 0, stream>>>(part, glen, spill, u, dinv, out);
    } else {
        float* deg  = (float*)d_ws;
        float* dinv = deg + N_NODES;
        float* xs   = dinv + N_NODES;
        float* s    = xs + N_NODES;
        float* u    = deg;
        const int TB = 256;
        const int gn = (N_NODES + TB - 1) / TB;
        const int ge = (N_EDGES + TB - 1) / TB;
        f_init <<<gn, TB, 0, stream>>>(deg);
        f_deg  <<<ge, TB, 0, stream>>>(dst, deg);
        f_node1<<<gn, TB, 0, stream>>>(x, deg, dinv, xs, s);
        f_sc1  <<<ge, TB, 0, stream>>>(src, dst, xs, dinv, s);
        f_node2<<<gn, TB, 0, stream>>>(s, dinv, W1, b1, W2, b2, u, out);
        f_sc2  <<<ge, TB, 0, stream>>>(src, dst, u, dinv, out);
    }
}

// Round 12
// 98.688 us; speedup vs baseline: 1.0075x; 1.0075x over previous
//
#include <hip/hip_runtime.h>

static constexpr int N_NODES = 250000;
static constexpr int N_EDGES = 5000000;

// ---- single-pass counting-sort by dst>>9 into 512-node buckets ----
static constexpr int NB    = 512;                       // partition blocks
static constexpr int CHUNK = 9768;                      // per-block edges; NB*CHUNK >= N_EDGES
static constexpr int NBK   = 512;                       // buckets (dst>>9); 489 used
static constexpr int NBUCK = (N_NODES + 511) / 512;     // 489 consumer blocks
static constexpr int BCAP  = 12288;                     // per-bucket region (mean 10225, +20 sigma)

// pack: bits 0..17 = src (N < 2^18), bits 20..28 = dst & 511
__device__ __forceinline__ unsigned pack_edge(unsigned s, unsigned d) {
    return s | ((d & 511u) << 20);
}

__global__ void z_init(unsigned* __restrict__ glen) {
    // glen[0..511] bucket cursors, glen[512] spill cursor, + pad to 520.
    int j = threadIdx.x;
    if (j < 520) glen[j] = 0;
}

// Single-pass partition: LDS histogram -> scan -> device reservation ->
// LDS bucket-scatter -> coalesced per-bucket run copy-out.  1024 threads.
__global__ void __launch_bounds__(1024, 8)
k_part_sp(const int* __restrict__ src, const int* __restrict__ dst,
          unsigned* __restrict__ glen, unsigned* __restrict__ part,
          uint2* __restrict__ spill) {
    __shared__ unsigned h[NBK];       // bucket counts (preserved)
    __shared__ unsigned loffE[NBK];   // exclusive scan
    __shared__ unsigned cur[NBK];     // scatter cursors
    __shared__ unsigned gb[NBK];      // reserved global offset within bucket region
    __shared__ unsigned ebuf[CHUNK];  // 38.2 KB bucket-ordered edges
    const int t = threadIdx.x;
    const int beg = blockIdx.x * CHUNK;
    const int end = min(beg + CHUNK, N_EDGES);

    if (t < NBK) h[t] = 0;
    __syncthreads();

    // ---- phase A: histogram dst buckets ----
    for (int e = beg + t * 4; e < end; e += 4096) {
        if (e + 4 <= end) {
            int4 d4 = *(const int4*)(dst + e);
            atomicAdd(&h[((unsigned)d4.x) >> 9], 1u);
            atomicAdd(&h[((unsigned)d4.y) >> 9], 1u);
            atomicAdd(&h[((unsigned)d4.z) >> 9], 1u);
            atomicAdd(&h[((unsigned)d4.w) >> 9], 1u);
        } else {
            for (int j = 0; j < 4 && e + j < end; ++j)
                atomicAdd(&h[((unsigned)dst[e + j]) >> 9], 1u);
        }
    }
    __syncthreads();

    // ---- phase B: block scan (threads < NBK) + one device reservation per bucket ----
    unsigned v = 0;
    if (t < NBK) { v = h[t]; loffE[t] = v; }
    __syncthreads();
    for (int off = 1; off < NBK; off <<= 1) {
        unsigned a = 0;
        if (t < NBK && t >= off) a = loffE[t - off];
        __syncthreads();
        if (t < NBK) loffE[t] += a;
        __syncthreads();
    }
    if (t < NBK) {
        loffE[t] -= v;              // exclusive
        cur[t] = loffE[t];
        gb[t] = v ? atomicAdd(&glen[t], v) : 0u;   // reserve once per (block,bucket)
    }
    __syncthreads();

    // ---- phase C: re-read edges (L2-warm), scatter into LDS by bucket ----
    for (int e = beg + t * 4; e < end; e += 4096) {
        if (e + 4 <= end) {
            int4 d4 = *(const int4*)(dst + e);
            int4 s4 = *(const int4*)(src + e);
            #pragma unroll
            for (int j = 0; j < 4; ++j) {
                int dd = j == 0 ? d4.x : j == 1 ? d4.y : j == 2 ? d4.z : d4.w;
                int ss = j == 0 ? s4.x : j == 1 ? s4.y : j == 2 ? s4.z : s4.w;
                unsigned b = ((unsigned)dd) >> 9;
                ebuf[atomicAdd(&cur[b], 1u)] = pack_edge((unsigned)ss, (unsigned)dd);
            }
        } else {
            for (int j = 0; j < 4 && e + j < end; ++j) {
                unsigned dd = (unsigned)dst[e + j], ss = (unsigned)src[e + j];
                ebuf[atomicAdd(&cur[dd >> 9], 1u)] = pack_edge(ss, dd);
            }
        }
    }
    __syncthreads();

    // ---- phase D: coalesced per-bucket run copy-out (+ spill, never in practice) ----
    const int g  = t >> 4;     // 64 groups of 16 lanes (groups never straddle a wave)
    const int gl = t & 15;
    for (int b = g; b < NBK; b += 64) {
        unsigned n = h[b];
        if (!n) continue;
        unsigned lo = loffE[b], base = gb[b];
        unsigned room = (base < (unsigned)BCAP) ? min(n, (unsigned)BCAP - base) : 0u;
        unsigned* dstp = part + (size_t)b * BCAP + base;
        for (unsigned i = gl; i < room; i += 16) dstp[i] = ebuf[lo + i];
        unsigned nsp = n - room;
        if (nsp) {   // overflow -> spill (uint2: src, full dst)
            unsigned spos = 0;
            if (gl == 0) spos = atomicAdd(&glen[NBK], nsp);
            spos = __shfl(spos, (int)((t & 63) & ~15), 64);
            for (unsigned i = gl; i < nsp; i += 16) {
                unsigned pe = ebuf[lo + room + i];
                spill[spos + i] = make_uint2(pe & 0x3FFFFu, ((unsigned)b << 9) | (pe >> 20));
            }
        }
    }
}

// consumer edge loop over bucket region [b*BCAP, b*BCAP+tot), 1024 threads
#define BUCKET_EDGE_LOOP(EDGE_OP)                                              \
    const unsigned st = (unsigned)blockIdx.x * (unsigned)BCAP;                 \
    const unsigned tot = min(glen[blockIdx.x], (unsigned)BCAP);                \
    const unsigned a1 = st + (tot & ~3u);                                      \
    for (unsigned k = st + threadIdx.x * 4u; k < a1; k += 4096u) {             \
        uint4 q = *(const uint4*)(part + k);                                   \
        EDGE_OP(q.x); EDGE_OP(q.y); EDGE_OP(q.z); EDGE_OP(q.w);                \
    }                                                                          \
    if (a1 + threadIdx.x < st + tot) { unsigned p = part[a1 + threadIdx.x]; EDGE_OP(p); }

// deg per node (LDS counts) fused with dinv = rsqrt(deg), xs = x*dinv
__global__ void __launch_bounds__(1024, 8)
k_deg_dinv(const unsigned* __restrict__ part, const unsigned* __restrict__ glen,
           const uint2* __restrict__ spill,
           const float* __restrict__ x,
           float* __restrict__ dinv, float* __restrict__ xs) {
    __shared__ unsigned cnt[512];
    if (threadIdx.x < 512) cnt[threadIdx.x] = 0;
    __syncthreads();
    #define DEG_OP(p) atomicAdd(&cnt[((p) >> 20) & 511u], 1u)
    BUCKET_EDGE_LOOP(DEG_OP)
    #undef DEG_OP
    unsigned sl = glen[NBK];
    for (unsigned k = threadIdx.x; k < sl; k += 1024u) {
        uint2 e = spill[k];
        if ((e.y >> 9) == (unsigned)blockIdx.x) atomicAdd(&cnt[e.y & 511u], 1u);
    }
    __syncthreads();
    if (threadIdx.x < 512) {
        int n = blockIdx.x * 512 + (int)threadIdx.x;
        if (n < N_NODES) {
            float di = rsqrtf((float)cnt[threadIdx.x] + 1.0f);  // +1 self-loop
            dinv[n] = di;
            xs[n] = x[n] * di;
        }
    }
}

// layer-1 aggregation + fused 16-wide MLP epilogue
__global__ void __launch_bounds__(1024, 8)
k_agg1(const unsigned* __restrict__ part, const unsigned* __restrict__ glen,
       const uint2* __restrict__ spill,
       const float* __restrict__ xs, const float* __restrict__ dinv,
       const float* __restrict__ W1, const float* __restrict__ b1,
       const float* __restrict__ W2, const float* __restrict__ b2,
       float* __restrict__ u, float* __restrict__ out) {
    __shared__ float acc[512];
    if (threadIdx.x < 512) acc[threadIdx.x] = 0.f;
    __syncthreads();
    #define AGG1_OP(p) atomicAdd(&acc[((p) >> 20) & 511u], xs[(p) & 0x3FFFFu])
    BUCKET_EDGE_LOOP(AGG1_OP)
    #undef AGG1_OP
    unsigned sl = glen[NBK];
    for (unsigned k = threadIdx.x; k < sl; k += 1024u) {
        uint2 e = spill[k];
        if ((e.y >> 9) == (unsigned)blockIdx.x) atomicAdd(&acc[e.y & 511u], xs[e.x]);
    }
    __syncthreads();
    if (threadIdx.x < 512) {
        int n = blockIdx.x * 512 + (int)threadIdx.x;
        if (n < N_NODES) {
            float di = dinv[n];
            float sv = di * (acc[threadIdx.x] + xs[n]);
            float t = 0.f;
            #pragma unroll
            for (int k = 0; k < 16; ++k)
                t = fmaf(fmaxf(fmaf(sv, W1[k], b1[k]), 0.f), W2[k], t);
            u[n] = t * di;
            out[n] = b2[0] + t * di * di;   // layer-2 self-loop + bias
        }
    }
}

// layer-2 aggregation: out += dinv * sum(u[src])
__global__ void __launch_bounds__(1024, 8)
k_agg2(const unsigned* __restrict__ part, const unsigned* __restrict__ glen,
       const uint2* __restrict__ spill,
       const float* __restrict__ u, const float* __restrict__ dinv,
       float* __restrict__ out) {
    __shared__ float acc[512];
    if (threadIdx.x < 512) acc[threadIdx.x] = 0.f;
    __syncthreads();
    #define AGG2_OP(p) atomicAdd(&acc[((p) >> 20) & 511u], u[(p) & 0x3FFFFu])
    BUCKET_EDGE_LOOP(AGG2_OP)
    #undef AGG2_OP
    unsigned sl = glen[NBK];
    for (unsigned k = threadIdx.x; k < sl; k += 1024u) {
        uint2 e = spill[k];
        if ((e.y >> 9) == (unsigned)blockIdx.x) atomicAdd(&acc[e.y & 511u], u[e.x]);
    }
    __syncthreads();
    if (threadIdx.x < 512) {
        int n = blockIdx.x * 512 + (int)threadIdx.x;
        if (n < N_NODES) out[n] += dinv[n] * acc[threadIdx.x];
    }
}

// ---- fallback path (device atomics) if ws is too small ----
__global__ void f_init(float* __restrict__ deg) {
    int n = blockIdx.x * blockDim.x + threadIdx.x;
    if (n < N_NODES) deg[n] = 1.0f;
}
__global__ void f_deg(const int* __restrict__ dst, float* __restrict__ deg) {
    int e = blockIdx.x * blockDim.x + threadIdx.x;
    if (e < N_EDGES) atomicAdd(&deg[dst[e]], 1.0f);
}
__global__ void f_node1(const float* __restrict__ x, const float* __restrict__ deg,
                        float* __restrict__ dinv, float* __restrict__ xs,
                        float* __restrict__ s) {
    int n = blockIdx.x * blockDim.x + threadIdx.x;
    if (n < N_NODES) {
        float di = rsqrtf(deg[n]);
        float xv = x[n];
        dinv[n] = di; xs[n] = xv * di; s[n] = xv * di * di;
    }
}
__global__ void f_sc1(const int* __restrict__ src, const int* __restrict__ dst,
                      const float* __restrict__ xs, const float* __restrict__ dinv,
                      float* __restrict__ s) {
    int e = blockIdx.x * blockDim.x + threadIdx.x;
    if (e < N_EDGES) atomicAdd(&s[dst[e]], xs[src[e]] * dinv[dst[e]]);
}
__global__ void f_node2(const float* __restrict__ s, const float* __restrict__ dinv,
                        const float* __restrict__ W1, const float* __restrict__ b1,
                        const float* __restrict__ W2, const float* __restrict__ b2,
                        float* __restrict__ u, float* __restrict__ out) {
    int n = blockIdx.x * blockDim.x + threadIdx.x;
    if (n < N_NODES) {
        float sv = s[n], acc = 0.0f;
        #pragma unroll
        for (int k = 0; k < 16; ++k)
            acc = fmaf(fmaxf(fmaf(sv, W1[k], b1[k]), 0.f), W2[k], acc);
        float di = dinv[n];
        u[n] = acc * di; out[n] = b2[0] + acc * di * di;
    }
}
__global__ void f_sc2(const int* __restrict__ src, const int* __restrict__ dst,
                      const float* __restrict__ u, const float* __restrict__ dinv,
                      float* __restrict__ out) {
    int e = blockIdx.x * blockDim.x + threadIdx.x;
    if (e < N_EDGES) atomicAdd(&out[dst[e]], u[src[e]] * dinv[dst[e]]);
}

extern "C" void kernel_launch(void* const* d_in, const int* in_sizes, int n_in,
                              void* d_out, int out_size, void* d_ws, size_t ws_size,
                              hipStream_t stream) {
    const float* x  = (const float*)d_in[0];
    const int*   ei = (const int*)d_in[1];
    const float* W1 = (const float*)d_in[2];
    const float* b1 = (const float*)d_in[3];
    const float* W2 = (const float*)d_in[4];
    const float* b2 = (const float*)d_in[5];
    float* out = (float*)d_out;
    const int* src = ei;
    const int* dst = ei + N_EDGES;

    // ws layout (u32 units): part[NBK*BCAP] | spill[N_EDGES uint2] | glen[520] | xs | dinv | u
    const size_t partN  = (size_t)NBK * BCAP;              // 6,291,456
    const size_t spillN = (size_t)N_EDGES * 2;             // uint2
    const size_t need   = (partN + spillN + 520 + 3 * (size_t)N_NODES) * 4;

    if (ws_size >= need) {
        unsigned* part  = (unsigned*)d_ws;
        uint2*    spill = (uint2*)(part + partN);
        unsigned* glen  = (unsigned*)(part + partN + spillN);
        float*    xs    = (float*)(glen + 520);
        float*    dinv  = xs + N_NODES;
        float*    u     = dinv + N_NODES;

        z_init    <<<1, 1024, 0, stream>>>(glen);
        k_part_sp <<<NB, 1024, 0, stream>>>(src, dst, glen, part, spill);
        k_deg_dinv<<<NBUCK, 1024, 0, stream>>>(part, glen, spill, x, dinv, xs);
        k_agg1    <<<NBUCK, 1024, 0, stream>>>(part, glen, spill, xs, dinv, W1, b1, W2, b2, u, out);
        k_agg2    <<<NBUCK, 1024, 0, stream>>>(part, glen, spill, u, dinv, out);
    } else {
        float* deg  = (float*)d_ws;
        float* dinv = deg + N_NODES;
        float* xs   = dinv + N_NODES;
        float* s    = xs + N_NODES;
        float* u    = deg;
        const int TB = 256;
        const int gn = (N_NODES + TB - 1) / TB;
        const int ge = (N_EDGES + TB - 1) / TB;
        f_init <<<gn, TB, 0, stream>>>(deg);
        f_deg  <<<ge, TB, 0, stream>>>(dst, deg);
        f_node1<<<gn, TB, 0, stream>>>(x, deg, dinv, xs, s);
        f_sc1  <<<ge, TB, 0, stream>>>(src, dst, xs, dinv, s);
        f_node2<<<gn, TB, 0, stream>>>(s, dinv, W1, b1, W2, b2, u, out);
        f_sc2  <<<ge, TB, 0, stream>>>(src, dst, u, dinv, out);
    }
}